// Round 2
// baseline (391.087 us; speedup 1.0000x reference)
//
#include <hip/hip_runtime.h>

typedef __bf16 bf16;
typedef unsigned int u32;
typedef __attribute__((ext_vector_type(4))) float f32x4;
typedef __attribute__((ext_vector_type(8))) __bf16 bf16x8;
typedef __attribute__((ext_vector_type(4))) __bf16 bf16x4;

#define MFMA(a, b, c) __builtin_amdgcn_mfma_f32_16x16x32_bf16((a), (b), (c), 0, 0, 0)

#define DIN 4096
#define DOUT 4096
#define DR 512

__device__ __forceinline__ void gll16(const void* g, void* l) {
  __builtin_amdgcn_global_load_lds((const __attribute__((address_space(1))) u32*)g,
                                   (__attribute__((address_space(3))) u32*)l, 16, 0, 0);
}

// ---------------- prep: V -> bf16 [512][4096] ----------------
__global__ __launch_bounds__(256) void prep_v_kernel(const float* __restrict__ vt,
                                                     const float* __restrict__ vd,
                                                     bf16* __restrict__ Vb) {
  int idx = blockIdx.x * 256 + threadIdx.x;  // one per 4 elems
  int e = idx * 4;
  int r = e >> 12, c = e & 4095;
  const float* src = (r < 64) ? (vt + ((size_t)r << 12) + c) : (vd + ((size_t)(r - 64) << 12) + c);
  float4 v = *reinterpret_cast<const float4*>(src);
  bf16x4 o = {(bf16)v.x, (bf16)v.y, (bf16)v.z, (bf16)v.w};
  *reinterpret_cast<bf16x4*>(Vb + e) = o;
}

// ---------------- prep: (U * s) -> bf16 [4096][512] ----------------
__global__ __launch_bounds__(256) void prep_u_kernel(const float* __restrict__ ut,
                                                     const float* __restrict__ ud,
                                                     const float* __restrict__ s,
                                                     bf16* __restrict__ Ub) {
  int idx = blockIdx.x * 256 + threadIdx.x;  // per 4 elems along r
  int o = idx >> 7;            // 128 quads per output row
  int rr = (idx & 127) * 4;
  const float* src = (rr < 64) ? (ut + (size_t)o * 64 + rr) : (ud + (size_t)o * 448 + (rr - 64));
  float4 v = *reinterpret_cast<const float4*>(src);
  float4 sv = *reinterpret_cast<const float4*>(s + rr);
  bf16x4 ov = {(bf16)(v.x * sv.x), (bf16)(v.y * sv.y), (bf16)(v.z * sv.z), (bf16)(v.w * sv.w)};
  *reinterpret_cast<bf16x4*>(Ub + (size_t)o * DR + rr) = ov;
}

// ---------------- GEMM1: t[8192][512] = x[8192][4096] * Vb[512][4096]^T ----------------
// BM=64 BN=128 BK=32, 256 threads (4 waves 2x2, wave tile 32x64), grid 512 (2 blocks/CU).
// B staged via global_load_lds with both-sides XOR swizzle: phys slot p = s ^ ((row>>1)&3).
// A (f32->bf16) reg-staged into pad-40 LDS (stride 5 quads, coprime 8 -> conflict-free).
__global__ __launch_bounds__(256) void gemm1_kernel(const float* __restrict__ X,
                                                    const bf16* __restrict__ Vb,
                                                    bf16* __restrict__ T) {
  __shared__ alignas(16) bf16 As[2][64 * 40];
  __shared__ alignas(16) bf16 Bs[2][128 * 32];

  const int tid = threadIdx.x;
  const int bid = blockIdx.x;
  // XCD-grouped: each XCD owns 16 consecutive M-panels x all 4 N-tiles.
  const int xcd = bid & 7, slot = bid >> 3;
  const int mt = xcd * 16 + (slot >> 2), nt = slot & 3;
  const int m0 = mt * 64, n0 = nt * 128;

  const int wid = tid >> 6, lane = tid & 63;
  const int wr = wid >> 1, wc = wid & 1;
  const int lr = lane & 15, kg = lane >> 4;
  const int ks = kg ^ ((lr >> 1) & 3);  // swizzled k-slot for B fragment reads

  // A staging: 64 rows x 4 segs of 8 f32
  const int arow = tid >> 2, aseg = tid & 3;
  const float* aG = X + (size_t)(m0 + arow) * DIN + aseg * 8;
  const int aWoff = arow * 40 + aseg * 8;

  // B staging: 8 chunks of 16 rows; wave wid owns chunks wid*2, wid*2+1.
  // lane -> phys (row = ci*16 + (lane>>2), slot = lane&3); source k-slot pre-swizzled.
  const int bs_ = (lane & 3) ^ ((lane >> 3) & 3);
  const int rl = lane >> 2;
  const int ci0 = wid * 2, ci1 = wid * 2 + 1;
  const bf16* bG0 = Vb + (size_t)(n0 + ci0 * 16 + rl) * DIN + bs_ * 8;
  const bf16* bG1 = Vb + (size_t)(n0 + ci1 * 16 + rl) * DIN + bs_ * 8;

  f32x4 acc[2][4];
  const f32x4 z = {0.f, 0.f, 0.f, 0.f};
#pragma unroll
  for (int i = 0; i < 2; ++i)
#pragma unroll
    for (int j = 0; j < 4; ++j) acc[i][j] = z;

  // prologue: stage kt=0 into buf 0
  {
    float4 v0 = *reinterpret_cast<const float4*>(aG);
    float4 v1 = *reinterpret_cast<const float4*>(aG + 4);
    bf16x8 w = {(bf16)v0.x, (bf16)v0.y, (bf16)v0.z, (bf16)v0.w,
                (bf16)v1.x, (bf16)v1.y, (bf16)v1.z, (bf16)v1.w};
    *reinterpret_cast<bf16x8*>(&As[0][aWoff]) = w;
    gll16(bG0, &Bs[0][ci0 * 512]);
    gll16(bG1, &Bs[0][ci1 * 512]);
  }
  __syncthreads();

  const int NT = DIN / 32;  // 128
  for (int kt = 0; kt < NT; ++kt) {
    const int cur = kt & 1;
    const bool pre = (kt + 1 < NT);
    float4 v0, v1;
    if (pre) {
      const float* ag = aG + (size_t)(kt + 1) * 32;
      v0 = *reinterpret_cast<const float4*>(ag);
      v1 = *reinterpret_cast<const float4*>(ag + 4);
      bf16* dB = (bf16*)Bs[cur ^ 1];
      gll16(bG0 + (size_t)(kt + 1) * 32, dB + ci0 * 512);
      gll16(bG1 + (size_t)(kt + 1) * 32, dB + ci1 * 512);
    }
    bf16x8 afr[2], bfr[4];
#pragma unroll
    for (int mi = 0; mi < 2; ++mi)
      afr[mi] = *reinterpret_cast<const bf16x8*>(&As[cur][(wr * 32 + mi * 16 + lr) * 40 + kg * 8]);
#pragma unroll
    for (int ni = 0; ni < 4; ++ni)
      bfr[ni] = *reinterpret_cast<const bf16x8*>(&Bs[cur][(wc * 64 + ni * 16 + lr) * 32 + ks * 8]);
#pragma unroll
    for (int mi = 0; mi < 2; ++mi)
#pragma unroll
      for (int ni = 0; ni < 4; ++ni)
        acc[mi][ni] = MFMA(afr[mi], bfr[ni], acc[mi][ni]);
    if (pre) {
      bf16x8 w = {(bf16)v0.x, (bf16)v0.y, (bf16)v0.z, (bf16)v0.w,
                  (bf16)v1.x, (bf16)v1.y, (bf16)v1.z, (bf16)v1.w};
      *reinterpret_cast<bf16x8*>(&As[cur ^ 1][aWoff]) = w;
    }
    __syncthreads();
  }

  // epilogue: C/D layout col = lane&15, row = (lane>>4)*4 + j
#pragma unroll
  for (int mi = 0; mi < 2; ++mi) {
    const int rbase = m0 + wr * 32 + mi * 16 + kg * 4;
#pragma unroll
    for (int ni = 0; ni < 4; ++ni) {
      const int c = n0 + wc * 64 + ni * 16 + lr;
      f32x4 a = acc[mi][ni];
#pragma unroll
      for (int j = 0; j < 4; ++j)
        T[(size_t)(rbase + j) * DR + c] = (bf16)a[j];
    }
  }
}

// ---------------- GEMM2: out[8192][4096] = t[8192][512] * Ub[4096][512]^T + bias ----------------
// BM=128 BN=128 BK=32, 256 threads (4 waves, wave tile 64x64), grid 2048.
// Both operands gll16-staged with the same both-sides XOR swizzle as gemm1-B.
__global__ __launch_bounds__(256) void gemm2_kernel(const bf16* __restrict__ T,
                                                    const bf16* __restrict__ Ub,
                                                    const float* __restrict__ bias,
                                                    float* __restrict__ Out) {
  __shared__ alignas(16) bf16 As[2][128 * 32];
  __shared__ alignas(16) bf16 Bs[2][128 * 32];

  const int tid = threadIdx.x;
  // XCD swizzle (2048 % 8 == 0 -> bijective)
  const int id = ((blockIdx.x & 7) << 8) | (blockIdx.x >> 3);
  const int mt = id >> 5, nt = id & 31;
  const int m0 = mt * 128, n0 = nt * 128;

  const int wid = tid >> 6, lane = tid & 63;
  const int wr = wid >> 1, wc = wid & 1;
  const int lr = lane & 15, kg = lane >> 4;
  const int ks = kg ^ ((lr >> 1) & 3);

  // staging: 8 chunks of 16 rows per operand; wave wid owns chunks wid*2, wid*2+1
  const int bs_ = (lane & 3) ^ ((lane >> 3) & 3);
  const int rl = lane >> 2;
  const int ci0 = wid * 2, ci1 = wid * 2 + 1;
  const bf16* aG0 = T + (size_t)(m0 + ci0 * 16 + rl) * DR + bs_ * 8;
  const bf16* aG1 = T + (size_t)(m0 + ci1 * 16 + rl) * DR + bs_ * 8;
  const bf16* bG0 = Ub + (size_t)(n0 + ci0 * 16 + rl) * DR + bs_ * 8;
  const bf16* bG1 = Ub + (size_t)(n0 + ci1 * 16 + rl) * DR + bs_ * 8;

  f32x4 acc[4][4];
  const f32x4 z = {0.f, 0.f, 0.f, 0.f};
#pragma unroll
  for (int i = 0; i < 4; ++i)
#pragma unroll
    for (int j = 0; j < 4; ++j) acc[i][j] = z;

  // prologue: stage kt=0 into buf 0
  {
    gll16(aG0, &As[0][ci0 * 512]);
    gll16(aG1, &As[0][ci1 * 512]);
    gll16(bG0, &Bs[0][ci0 * 512]);
    gll16(bG1, &Bs[0][ci1 * 512]);
  }
  __syncthreads();

  const int NT = DR / 32;  // 16
  for (int kt = 0; kt < NT; ++kt) {
    const int cur = kt & 1;
    const bool pre = (kt + 1 < NT);
    if (pre) {
      const size_t koff = (size_t)(kt + 1) * 32;
      bf16* dA = (bf16*)As[cur ^ 1];
      bf16* dB = (bf16*)Bs[cur ^ 1];
      gll16(aG0 + koff, dA + ci0 * 512);
      gll16(aG1 + koff, dA + ci1 * 512);
      gll16(bG0 + koff, dB + ci0 * 512);
      gll16(bG1 + koff, dB + ci1 * 512);
    }
    bf16x8 afr[4], bfr[4];
#pragma unroll
    for (int mi = 0; mi < 4; ++mi)
      afr[mi] = *reinterpret_cast<const bf16x8*>(&As[cur][(wr * 64 + mi * 16 + lr) * 32 + ks * 8]);
#pragma unroll
    for (int ni = 0; ni < 4; ++ni)
      bfr[ni] = *reinterpret_cast<const bf16x8*>(&Bs[cur][(wc * 64 + ni * 16 + lr) * 32 + ks * 8]);
#pragma unroll
    for (int mi = 0; mi < 4; ++mi)
#pragma unroll
      for (int ni = 0; ni < 4; ++ni)
        acc[mi][ni] = MFMA(afr[mi], bfr[ni], acc[mi][ni]);
    __syncthreads();
  }

  // epilogue with bias
#pragma unroll
  for (int ni = 0; ni < 4; ++ni) {
    const int c = n0 + wc * 64 + ni * 16 + lr;
    const float bv = bias[c];
#pragma unroll
    for (int mi = 0; mi < 4; ++mi) {
      const int rbase = m0 + wr * 64 + mi * 16 + kg * 4;
      f32x4 a = acc[mi][ni];
#pragma unroll
      for (int j = 0; j < 4; ++j)
        Out[(size_t)(rbase + j) * DOUT + c] = a[j] + bv;
    }
  }
}

extern "C" void kernel_launch(void* const* d_in, const int* in_sizes, int n_in,
                              void* d_out, int out_size, void* d_ws, size_t ws_size,
                              hipStream_t stream) {
  const float* x = (const float*)d_in[0];
  const float* u_t = (const float*)d_in[1];
  const float* s = (const float*)d_in[2];
  const float* v_t = (const float*)d_in[3];
  const float* u_d = (const float*)d_in[4];
  const float* v_d = (const float*)d_in[5];
  const float* bias = (const float*)d_in[6];
  float* out = (float*)d_out;

  bf16* Vb = (bf16*)d_ws;                                // 4 MiB: [512][4096]
  bf16* Ub = (bf16*)((char*)d_ws + (4u << 20));          // 4 MiB: [4096][512]
  bf16* T = (bf16*)((char*)d_ws + (8u << 20));           // 8 MiB: [8192][512]

  hipLaunchKernelGGL(prep_v_kernel, dim3(2048), dim3(256), 0, stream, v_t, v_d, Vb);
  hipLaunchKernelGGL(prep_u_kernel, dim3(2048), dim3(256), 0, stream, u_t, u_d, s, Ub);
  hipLaunchKernelGGL(gemm1_kernel, dim3(512), dim3(256), 0, stream, x, Vb, T);
  hipLaunchKernelGGL(gemm2_kernel, dim3(2048), dim3(256), 0, stream, T, Ub, bias, out);
}

// Round 3
// 387.550 us; speedup vs baseline: 1.0091x; 1.0091x over previous
//
#include <hip/hip_runtime.h>

typedef __bf16 bf16;
typedef unsigned int u32;
typedef __attribute__((ext_vector_type(4))) float f32x4;
typedef __attribute__((ext_vector_type(8))) __bf16 bf16x8;
typedef __attribute__((ext_vector_type(4))) __bf16 bf16x4;

#define MFMA_(a, b, c) __builtin_amdgcn_mfma_f32_16x16x32_bf16((a), (b), (c), 0, 0, 0)

#define DIN 4096
#define DOUT 4096
#define DR 512

__device__ __forceinline__ void gll16(const void* g, void* l) {
  __builtin_amdgcn_global_load_lds((const __attribute__((address_space(1))) u32*)g,
                                   (__attribute__((address_space(3))) u32*)l, 16, 0, 0);
}

#define FENCE() asm volatile("" ::: "memory")
#define SCHEDB() __builtin_amdgcn_sched_barrier(0)
#define WAITVM8() do { SCHEDB(); asm volatile("s_waitcnt vmcnt(8)" ::: "memory"); } while (0)
#define WAITLGKM0() asm volatile("s_waitcnt lgkmcnt(0)" ::: "memory")
#define BARRIER() do { FENCE(); __builtin_amdgcn_s_barrier(); SCHEDB(); } while (0)

// ---------------- prep: V -> bf16 [512][4096] ----------------
__global__ __launch_bounds__(256) void prep_v_kernel(const float* __restrict__ vt,
                                                     const float* __restrict__ vd,
                                                     bf16* __restrict__ Vb) {
  int idx = blockIdx.x * 256 + threadIdx.x;
  int e = idx * 4;
  int r = e >> 12, c = e & 4095;
  const float* src = (r < 64) ? (vt + ((size_t)r << 12) + c) : (vd + ((size_t)(r - 64) << 12) + c);
  float4 v = *reinterpret_cast<const float4*>(src);
  bf16x4 o = {(bf16)v.x, (bf16)v.y, (bf16)v.z, (bf16)v.w};
  *reinterpret_cast<bf16x4*>(Vb + e) = o;
}

// ---------------- prep: (U * s) -> bf16 [4096][512] ----------------
__global__ __launch_bounds__(256) void prep_u_kernel(const float* __restrict__ ut,
                                                     const float* __restrict__ ud,
                                                     const float* __restrict__ s,
                                                     bf16* __restrict__ Ub) {
  int idx = blockIdx.x * 256 + threadIdx.x;
  int o = idx >> 7;
  int rr = (idx & 127) * 4;
  const float* src = (rr < 64) ? (ut + (size_t)o * 64 + rr) : (ud + (size_t)o * 448 + (rr - 64));
  float4 v = *reinterpret_cast<const float4*>(src);
  float4 sv = *reinterpret_cast<const float4*>(s + rr);
  bf16x4 ov = {(bf16)(v.x * sv.x), (bf16)(v.y * sv.y), (bf16)(v.z * sv.z), (bf16)(v.w * sv.w)};
  *reinterpret_cast<bf16x4*>(Ub + (size_t)o * DR + rr) = ov;
}

// ---------------- GEMM1: t[8192][512] = x[8192][4096] * Vb[512][4096]^T ----------------
// BM=64 BN=128 BK=32, 256 thr (4 waves 2x2, wave 32x64). 4 LDS buffers, 2-deep
// prefetch, counted vmcnt(8), one raw barrier/iter. A reg-staged f32->bf16
// (4-deep reg rotation, swizzled ds_write); B via gll16 with pre-swizzled source.
__global__ __launch_bounds__(256) void gemm1_kernel(const float* __restrict__ X,
                                                    const bf16* __restrict__ Vb,
                                                    bf16* __restrict__ T) {
  __shared__ alignas(16) bf16 As[4 * 2048];  // 4 bufs x [64 rows][4 slots of 8]
  __shared__ alignas(16) bf16 Bs[4 * 4096];  // 4 bufs x [128 rows][4 slots of 8]

  const int tid = threadIdx.x, bid = blockIdx.x;
  const int xcd = bid & 7, slot = bid >> 3;
  const int mt = xcd * 16 + (slot >> 2), nt = slot & 3;
  const int m0 = mt * 64, n0 = nt * 128;

  const int wid = tid >> 6, lane = tid & 63;
  const int wr = wid >> 1, wc = wid & 1;
  const int lr = lane & 15, kg = lane >> 4;
  const int ks = kg ^ ((lr >> 1) & 3);  // phys k-slot for frag reads

  // A staging: thread -> (row=tid>>2, logical slot=tid&3); phys = sl ^ ((row>>1)&3)
  const int arow = tid >> 2, asl = tid & 3;
  const int aphys = asl ^ ((arow >> 1) & 3);
  const float* aG = X + (size_t)(m0 + arow) * DIN + asl * 8;
  const int awoff = (arow * 4 + aphys) * 8;

  // B staging via gll16: wave wid owns chunks c0,c1 (16 rows each); linear LDS dest,
  // source k-slot pre-swizzled: logical = (lane&3) ^ ((lane>>3)&3)
  const int c0 = wid * 2, c1 = wid * 2 + 1;
  const int srcsl = (lane & 3) ^ ((lane >> 3) & 3);
  const bf16* bG0 = Vb + (size_t)(n0 + c0 * 16 + (lane >> 2)) * DIN + srcsl * 8;
  const bf16* bG1 = Vb + (size_t)(n0 + c1 * 16 + (lane >> 2)) * DIN + srcsl * 8;

  int aoff[2], boff[4];
#pragma unroll
  for (int mi = 0; mi < 2; ++mi) aoff[mi] = ((wr * 32 + mi * 16 + lr) * 4 + ks) * 8;
#pragma unroll
  for (int ni = 0; ni < 4; ++ni) boff[ni] = ((wc * 64 + ni * 16 + lr) * 4 + ks) * 8;

  f32x4 acc[2][4];
  const f32x4 z = {0.f, 0.f, 0.f, 0.f};
#pragma unroll
  for (int i = 0; i < 2; ++i)
#pragma unroll
    for (int j = 0; j < 4; ++j) acc[i][j] = z;

  float4 rA[4][2];

  // ---- prologue: queue = A0 | {B0,A1} | {B1,A2} ----
  rA[0][0] = *reinterpret_cast<const float4*>(aG);
  rA[0][1] = *reinterpret_cast<const float4*>(aG + 4);
  SCHEDB();
  gll16(bG0, &Bs[0 * 4096 + c0 * 512]);
  gll16(bG1, &Bs[0 * 4096 + c1 * 512]);
  rA[1][0] = *reinterpret_cast<const float4*>(aG + 32);
  rA[1][1] = *reinterpret_cast<const float4*>(aG + 36);
  SCHEDB();
  gll16(bG0 + 32, &Bs[1 * 4096 + c0 * 512]);
  gll16(bG1 + 32, &Bs[1 * 4096 + c1 * 512]);
  rA[2][0] = *reinterpret_cast<const float4*>(aG + 64);
  rA[2][1] = *reinterpret_cast<const float4*>(aG + 68);
  WAITVM8();  // A0 landed
  {
    float4 v0 = rA[0][0], v1 = rA[0][1];
    bf16x8 w = {(bf16)v0.x, (bf16)v0.y, (bf16)v0.z, (bf16)v0.w,
                (bf16)v1.x, (bf16)v1.y, (bf16)v1.z, (bf16)v1.w};
    *reinterpret_cast<bf16x8*>(&As[0 * 2048 + awoff]) = w;
  }

#define G1_BODY(t, RB, WB, PB, SW, SP)                                               \
  do {                                                                               \
    const int kt2 = ((t) + 2 < 128) ? (t) + 2 : 127;                                 \
    const int kt3 = ((t) + 3 < 128) ? (t) + 3 : 127;                                 \
    gll16(bG0 + (size_t)kt2 * 32, &Bs[(PB) * 4096 + c0 * 512]);                      \
    gll16(bG1 + (size_t)kt2 * 32, &Bs[(PB) * 4096 + c1 * 512]);                      \
    rA[SP][0] = *reinterpret_cast<const float4*>(aG + (size_t)kt3 * 32);             \
    rA[SP][1] = *reinterpret_cast<const float4*>(aG + (size_t)kt3 * 32 + 4);         \
    WAITVM8(); /* B(t), A(t+1) landed */                                             \
    {                                                                                \
      float4 v0 = rA[SW][0], v1 = rA[SW][1];                                         \
      bf16x8 w = {(bf16)v0.x, (bf16)v0.y, (bf16)v0.z, (bf16)v0.w,                    \
                  (bf16)v1.x, (bf16)v1.y, (bf16)v1.z, (bf16)v1.w};                   \
      *reinterpret_cast<bf16x8*>(&As[(WB) * 2048 + awoff]) = w;                      \
    }                                                                                \
    WAITLGKM0();                                                                     \
    BARRIER();                                                                       \
    bf16x8 afr[2], bfr[4];                                                           \
    afr[0] = *reinterpret_cast<const bf16x8*>(&As[(RB) * 2048 + aoff[0]]);           \
    afr[1] = *reinterpret_cast<const bf16x8*>(&As[(RB) * 2048 + aoff[1]]);           \
    bfr[0] = *reinterpret_cast<const bf16x8*>(&Bs[(RB) * 4096 + boff[0]]);           \
    bfr[1] = *reinterpret_cast<const bf16x8*>(&Bs[(RB) * 4096 + boff[1]]);           \
    bfr[2] = *reinterpret_cast<const bf16x8*>(&Bs[(RB) * 4096 + boff[2]]);           \
    bfr[3] = *reinterpret_cast<const bf16x8*>(&Bs[(RB) * 4096 + boff[3]]);           \
    _Pragma("unroll") for (int mi = 0; mi < 2; ++mi)                                 \
        _Pragma("unroll") for (int ni = 0; ni < 4; ++ni)                             \
            acc[mi][ni] = MFMA_(afr[mi], bfr[ni], acc[mi][ni]);                      \
  } while (0)

  for (int tb = 0; tb < 128; tb += 4) {
    G1_BODY(tb + 0, 0, 1, 2, 1, 3);
    G1_BODY(tb + 1, 1, 2, 3, 2, 0);
    G1_BODY(tb + 2, 2, 3, 0, 3, 1);
    G1_BODY(tb + 3, 3, 0, 1, 0, 2);
  }
#undef G1_BODY

#pragma unroll
  for (int mi = 0; mi < 2; ++mi) {
    const int rbase = m0 + wr * 32 + mi * 16 + kg * 4;
#pragma unroll
    for (int ni = 0; ni < 4; ++ni) {
      const int c = n0 + wc * 64 + ni * 16 + lr;
      f32x4 a = acc[mi][ni];
#pragma unroll
      for (int j = 0; j < 4; ++j)
        T[(size_t)(rbase + j) * DR + c] = (bf16)a[j];
    }
  }
}

// ---------------- GEMM2: out[8192][4096] = t[8192][512] * Ub[4096][512]^T + bias ----------------
// BM=128 BN=128 BK=32, 256 thr (4 waves 2x2, wave 64x64). 4 LDS buffers, 2-deep
// prefetch, counted vmcnt(8), one raw barrier/iter. Both operands gll16 + swizzle.
__global__ __launch_bounds__(256) void gemm2_kernel(const bf16* __restrict__ Tt,
                                                    const bf16* __restrict__ Ub,
                                                    const float* __restrict__ bias,
                                                    float* __restrict__ Out) {
  __shared__ alignas(16) bf16 As[4 * 4096];
  __shared__ alignas(16) bf16 Bs[4 * 4096];

  const int tid = threadIdx.x;
  const int id = ((blockIdx.x & 7) << 8) | (blockIdx.x >> 3);  // bijective XCD swizzle
  const int mt = id >> 5, nt = id & 31;
  const int m0 = mt * 128, n0 = nt * 128;

  const int wid = tid >> 6, lane = tid & 63;
  const int wr = wid >> 1, wc = wid & 1;
  const int lr = lane & 15, kg = lane >> 4;
  const int ks = kg ^ ((lr >> 1) & 3);

  const int c0 = wid * 2, c1 = wid * 2 + 1;
  const int srcsl = (lane & 3) ^ ((lane >> 3) & 3);
  const bf16* aG0 = Tt + (size_t)(m0 + c0 * 16 + (lane >> 2)) * DR + srcsl * 8;
  const bf16* aG1 = Tt + (size_t)(m0 + c1 * 16 + (lane >> 2)) * DR + srcsl * 8;
  const bf16* bG0 = Ub + (size_t)(n0 + c0 * 16 + (lane >> 2)) * DR + srcsl * 8;
  const bf16* bG1 = Ub + (size_t)(n0 + c1 * 16 + (lane >> 2)) * DR + srcsl * 8;

  int aoff[4], boff[4];
#pragma unroll
  for (int mi = 0; mi < 4; ++mi) aoff[mi] = ((wr * 64 + mi * 16 + lr) * 4 + ks) * 8;
#pragma unroll
  for (int ni = 0; ni < 4; ++ni) boff[ni] = ((wc * 64 + ni * 16 + lr) * 4 + ks) * 8;

  f32x4 acc[4][4];
  const f32x4 z = {0.f, 0.f, 0.f, 0.f};
#pragma unroll
  for (int i = 0; i < 4; ++i)
#pragma unroll
    for (int j = 0; j < 4; ++j) acc[i][j] = z;

  // ---- prologue: S(0) | S(1) ----
  gll16(aG0, &As[0 * 4096 + c0 * 512]);
  gll16(aG1, &As[0 * 4096 + c1 * 512]);
  gll16(bG0, &Bs[0 * 4096 + c0 * 512]);
  gll16(bG1, &Bs[0 * 4096 + c1 * 512]);
  SCHEDB();
  gll16(aG0 + 32, &As[1 * 4096 + c0 * 512]);
  gll16(aG1 + 32, &As[1 * 4096 + c1 * 512]);
  gll16(bG0 + 32, &Bs[1 * 4096 + c0 * 512]);
  gll16(bG1 + 32, &Bs[1 * 4096 + c1 * 512]);
  SCHEDB();

#define G2_BODY(t, RB, PB)                                                           \
  do {                                                                               \
    const int kt2 = ((t) + 2 < 16) ? (t) + 2 : 15;                                   \
    gll16(aG0 + (size_t)kt2 * 32, &As[(PB) * 4096 + c0 * 512]);                      \
    gll16(aG1 + (size_t)kt2 * 32, &As[(PB) * 4096 + c1 * 512]);                      \
    gll16(bG0 + (size_t)kt2 * 32, &Bs[(PB) * 4096 + c0 * 512]);                      \
    gll16(bG1 + (size_t)kt2 * 32, &Bs[(PB) * 4096 + c1 * 512]);                      \
    WAITVM8(); /* S(t) landed */                                                     \
    BARRIER();                                                                       \
    bf16x8 afr[4], bfr[4];                                                           \
    _Pragma("unroll") for (int mi = 0; mi < 4; ++mi)                                 \
        afr[mi] = *reinterpret_cast<const bf16x8*>(&As[(RB) * 4096 + aoff[mi]]);     \
    _Pragma("unroll") for (int ni = 0; ni < 4; ++ni)                                 \
        bfr[ni] = *reinterpret_cast<const bf16x8*>(&Bs[(RB) * 4096 + boff[ni]]);     \
    _Pragma("unroll") for (int mi = 0; mi < 4; ++mi)                                 \
        _Pragma("unroll") for (int ni = 0; ni < 4; ++ni)                             \
            acc[mi][ni] = MFMA_(afr[mi], bfr[ni], acc[mi][ni]);                      \
  } while (0)

  for (int tb = 0; tb < 16; tb += 4) {
    G2_BODY(tb + 0, 0, 2);
    G2_BODY(tb + 1, 1, 3);
    G2_BODY(tb + 2, 2, 0);
    G2_BODY(tb + 3, 3, 1);
  }
#undef G2_BODY

#pragma unroll
  for (int ni = 0; ni < 4; ++ni) {
    const int c = n0 + wc * 64 + ni * 16 + lr;
    const float bv = bias[c];
#pragma unroll
    for (int mi = 0; mi < 4; ++mi) {
      const int rbase = m0 + wr * 64 + mi * 16 + kg * 4;
      f32x4 a = acc[mi][ni];
#pragma unroll
      for (int j = 0; j < 4; ++j)
        Out[(size_t)(rbase + j) * DOUT + c] = a[j] + bv;
    }
  }
}

extern "C" void kernel_launch(void* const* d_in, const int* in_sizes, int n_in,
                              void* d_out, int out_size, void* d_ws, size_t ws_size,
                              hipStream_t stream) {
  const float* x = (const float*)d_in[0];
  const float* u_t = (const float*)d_in[1];
  const float* s = (const float*)d_in[2];
  const float* v_t = (const float*)d_in[3];
  const float* u_d = (const float*)d_in[4];
  const float* v_d = (const float*)d_in[5];
  const float* bias = (const float*)d_in[6];
  float* out = (float*)d_out;

  bf16* Vb = (bf16*)d_ws;                        // 4 MiB: [512][4096]
  bf16* Ub = (bf16*)((char*)d_ws + (4u << 20));  // 4 MiB: [4096][512]
  bf16* T = (bf16*)((char*)d_ws + (8u << 20));   // 8 MiB: [8192][512]

  hipLaunchKernelGGL(prep_v_kernel, dim3(2048), dim3(256), 0, stream, v_t, v_d, Vb);
  hipLaunchKernelGGL(prep_u_kernel, dim3(2048), dim3(256), 0, stream, u_t, u_d, s, Ub);
  hipLaunchKernelGGL(gemm1_kernel, dim3(512), dim3(256), 0, stream, x, Vb, T);
  hipLaunchKernelGGL(gemm2_kernel, dim3(2048), dim3(256), 0, stream, T, Ub, bias, out);
}